// Round 2
// baseline (27383.813 us; speedup 1.0000x reference)
//
#include <hip/hip_runtime.h>
#include <hip/hip_bf16.h>

#define S_LEN 512
#define BATCH 64
#define EMB_D 256
#define HID   512
#define NTAG  5

__device__ __forceinline__ float bf2f(unsigned short u) {
  union { unsigned int i; float f; } v; v.i = ((unsigned int)u) << 16; return v.f;
}
__device__ __forceinline__ float sigm(float x) { return 1.0f / (1.0f + __expf(-x)); }

// ---------------- embedding gather: x[s][b][e] = emb[text[b][s]][e] ----------------
__global__ void k_embed(const int* __restrict__ text, const float* __restrict__ emb,
                        float* __restrict__ x)
{
  const int total = S_LEN * BATCH * EMB_D;
  for (int idx = blockIdx.x * blockDim.x + threadIdx.x; idx < total;
       idx += gridDim.x * blockDim.x) {
    int e  = idx & (EMB_D - 1);
    int sb = idx >> 8;          // EMB_D=256
    int b  = sb & (BATCH - 1);
    int s  = sb >> 6;           // BATCH=64
    int row = text[b * S_LEN + s];
    x[idx] = emb[row * EMB_D + e];
  }
}

// ---------------- persistent BiLSTM ----------------
// grid = 256 blocks (d = bid&1, jb = bid>>1 owns hidden units k0..k0+3 of that dir)
// block = 256 threads: b = tid&63 (batch row), kk = tid>>6 (hidden unit within slice)
// LDS: W rows [16][772] fp32 (rows r=q*4+kl, cols 0..255 = W_ih, 256..767 = W_hh),
//      bias[16], z-chunk [64][132].
__launch_bounds__(256, 1)
__global__ void k_lstm(const float* __restrict__ x,
                       const float* __restrict__ wih_f, const float* __restrict__ whh_f,
                       const float* __restrict__ bih_f, const float* __restrict__ bhh_f,
                       const float* __restrict__ wih_b, const float* __restrict__ whh_b,
                       const float* __restrict__ bih_b, const float* __restrict__ bhh_b,
                       float* __restrict__ h_buf, __hip_bfloat16* __restrict__ vec,
                       int* __restrict__ bar)
{
  extern __shared__ float smem[];
  float* Wl   = smem;             // 16*772
  float* bl   = smem + 16 * 772;  // 16
  float* zbuf = bl + 16;          // 64*132

  const int bid = blockIdx.x;
  const int d   = bid & 1;
  const int jb  = bid >> 1;
  const int k0  = jb * 4;
  const int tid = threadIdx.x;
  const int b   = tid & 63;
  const int kk  = tid >> 6;

  const float* wih = d ? wih_b : wih_f;
  const float* whh = d ? whh_b : whh_f;
  const float* bih = d ? bih_b : bih_f;
  const float* bhh = d ? bhh_b : bhh_f;

  for (int f = tid; f < 16 * 768; f += 256) {
    int r = f / 768, col = f - r * 768;
    int q = r >> 2, kl = r & 3;
    int jrow = q * HID + k0 + kl;
    Wl[r * 772 + col] = (col < EMB_D) ? wih[jrow * EMB_D + col]
                                      : whh[jrow * HID + (col - EMB_D)];
  }
  if (tid < 16) {
    int q = tid >> 2, kl = tid & 3;
    int jrow = q * HID + k0 + kl;
    bl[tid] = bih[jrow] + bhh[jrow];
  }
  __syncthreads();

  const float* W0 = Wl + (0  + kk) * 772;   // i
  const float* W1 = Wl + (4  + kk) * 772;   // f
  const float* W2 = Wl + (8  + kk) * 772;   // g
  const float* W3 = Wl + (12 + kk) * 772;   // o

  float c_st = 0.f;
  float* hbase = h_buf + d * (2 * BATCH * HID);
  const int nblk = gridDim.x;

  for (int it = 0; it < S_LEN; ++it) {
    const int t = d ? (S_LEN - 1 - it) : it;
    const float* hprev = hbase + (it & 1) * (BATCH * HID);
    float*       hnext = hbase + ((it & 1) ^ 1) * (BATCH * HID);

    // ---- grid barrier (monotonic counter; zeroed per launch) ----
    __syncthreads();
    if (tid == 0) {
      __threadfence();
      atomicAdd(bar, 1);
      const int target = nblk * (it + 1);
      while (__hip_atomic_load(bar, __ATOMIC_RELAXED, __HIP_MEMORY_SCOPE_AGENT) < target)
        __builtin_amdgcn_s_sleep(2);
      __threadfence();
    }
    __syncthreads();

    float g0 = bl[kk], g1 = bl[4 + kk], g2 = bl[8 + kk], g3 = bl[12 + kk];
    const float4* xsrc = (const float4*)(x + (size_t)t * (BATCH * EMB_D));
    const float4* hsrc = (const float4*)hprev;

    for (int ch = 0; ch < 6; ++ch) {
      __syncthreads();
      if (ch < 2) {
        for (int u = tid; u < 2048; u += 256) {
          int bb = u >> 5, e4 = u & 31;
          float4 v = xsrc[bb * (EMB_D / 4) + ch * 32 + e4];
          *(float4*)(zbuf + bb * 132 + e4 * 4) = v;
        }
      } else {
        int cb = (ch - 2) * 32;
        for (int u = tid; u < 2048; u += 256) {
          int bb = u >> 5, e4 = u & 31;
          float4 v = hsrc[bb * (HID / 4) + cb + e4];
          *(float4*)(zbuf + bb * 132 + e4 * 4) = v;
        }
      }
      __syncthreads();
      const float* zrow = zbuf + b * 132;
      const int cbase = ch * 128;
      #pragma unroll 8
      for (int e4 = 0; e4 < 32; ++e4) {
        float4 z = *(const float4*)(zrow + e4 * 4);
        const int c0 = cbase + e4 * 4;
        float4 a;
        a = *(const float4*)(W0 + c0); g0 += a.x*z.x + a.y*z.y + a.z*z.z + a.w*z.w;
        a = *(const float4*)(W1 + c0); g1 += a.x*z.x + a.y*z.y + a.z*z.z + a.w*z.w;
        a = *(const float4*)(W2 + c0); g2 += a.x*z.x + a.y*z.y + a.z*z.z + a.w*z.w;
        a = *(const float4*)(W3 + c0); g3 += a.x*z.x + a.y*z.y + a.z*z.z + a.w*z.w;
      }
    }

    const float ig = sigm(g0), fg = sigm(g1), gg = tanhf(g2), og = sigm(g3);
    c_st = fg * c_st + ig * gg;
    const float hv = og * tanhf(c_st);
    hnext[b * HID + k0 + kk] = hv;
    vec[((size_t)t * BATCH + b) * (2 * HID) + d * HID + k0 + kk] = __float2bfloat16(hv);
  }
}

// ---------------- heads: em[s][b][j] = vec[s][b][:] . w[j][:] + bias[j] ----------------
__global__ void k_heads(const __hip_bfloat16* __restrict__ vec,
                        const float* __restrict__ sbj_w, const float* __restrict__ sbj_b,
                        const float* __restrict__ obj_w, const float* __restrict__ obj_b,
                        float* __restrict__ em_s, float* __restrict__ em_o)
{
  const int wid  = blockIdx.x * 4 + (threadIdx.x >> 6);
  const int lane = threadIdx.x & 63;
  if (wid >= S_LEN * BATCH) return;
  const unsigned short* vrow = (const unsigned short*)(vec + (size_t)wid * (2 * HID));
  uint4 p0 = *(const uint4*)(vrow + lane * 16);
  uint4 p1 = *(const uint4*)(vrow + lane * 16 + 8);
  unsigned int pw[8] = { p0.x, p0.y, p0.z, p0.w, p1.x, p1.y, p1.z, p1.w };
  float z[16];
  #pragma unroll
  for (int i = 0; i < 8; ++i) {
    z[2 * i]     = bf2f((unsigned short)(pw[i] & 0xffffu));
    z[2 * i + 1] = bf2f((unsigned short)(pw[i] >> 16));
  }
  #pragma unroll
  for (int r = 0; r < 10; ++r) {
    const float* wr = (r < 5) ? (sbj_w + r * (2 * HID)) : (obj_w + (r - 5) * (2 * HID));
    float p = 0.f;
    #pragma unroll
    for (int m4 = 0; m4 < 4; ++m4) {
      float4 w4 = *(const float4*)(wr + lane * 16 + m4 * 4);
      p += w4.x * z[m4*4] + w4.y * z[m4*4+1] + w4.z * z[m4*4+2] + w4.w * z[m4*4+3];
    }
    #pragma unroll
    for (int off = 32; off; off >>= 1) p += __shfl_down(p, off);
    if (lane == 0) {
      if (r < 5) em_s[(size_t)wid * NTAG + r]       = p + sbj_b[r];
      else       em_o[(size_t)wid * NTAG + (r - 5)] = p + obj_b[r - 5];
    }
  }
}

// ---------------- CRF NLL per (crf, batch): one wave each ----------------
__global__ void k_crf(const float* __restrict__ em_s, const float* __restrict__ em_o,
                      const int* __restrict__ sbjs, const int* __restrict__ objs,
                      const int* __restrict__ text,
                      const float* __restrict__ s_st, const float* __restrict__ s_en,
                      const float* __restrict__ s_tr,
                      const float* __restrict__ o_st, const float* __restrict__ o_en,
                      const float* __restrict__ o_tr,
                      float* __restrict__ perb, float* __restrict__ cntb)
{
  const int c = blockIdx.x & 1;
  const int b = blockIdx.x >> 1;
  const int j = threadIdx.x;

  const float* em    = c ? em_o : em_s;
  const int*   tags  = c ? objs : sbjs;
  const float* start = c ? o_st : s_st;
  const float* endv  = c ? o_en : s_en;
  const float* trans = c ? o_tr : s_tr;

  // numerator + token count, parallel over s
  float num = 0.f, cnt = 0.f;
  for (int s = j; s < S_LEN; s += 64) {
    const int m = (text[b * S_LEN + s] != 0) ? 1 : 0;
    cnt += (float)m;
    const int tg = tags[b * S_LEN + s];
    if (s == 0) {
      num += start[tg] + em[(size_t)b * NTAG + tg];
    } else if (m) {
      const int tp = tags[b * S_LEN + s - 1];
      num += trans[tp * NTAG + tg] + em[((size_t)s * BATCH + b) * NTAG + tg];
    }
  }
  #pragma unroll
  for (int off = 32; off; off >>= 1) { num += __shfl_down(num, off); cnt += __shfl_down(cnt, off); }
  num = __shfl(num, 0); cnt = __shfl(cnt, 0);
  const int seq_end = (int)cnt - 1;
  if (j == 0) num += endv[tags[b * S_LEN + seq_end]];

  // forward algorithm on lanes 0..4
  float tr0 = 0, tr1 = 0, tr2 = 0, tr3 = 0, tr4 = 0, st = 0, en = 0;
  if (j < NTAG) {
    tr0 = trans[0 * NTAG + j]; tr1 = trans[1 * NTAG + j]; tr2 = trans[2 * NTAG + j];
    tr3 = trans[3 * NTAG + j]; tr4 = trans[4 * NTAG + j];
    st = start[j]; en = endv[j];
  }
  float alpha = (j < NTAG) ? (st + em[(size_t)b * NTAG + j]) : -1e30f;
  for (int s = 1; s < S_LEN; ++s) {
    const float a0 = __shfl(alpha, 0), a1 = __shfl(alpha, 1), a2 = __shfl(alpha, 2),
                a3 = __shfl(alpha, 3), a4 = __shfl(alpha, 4);
    const int m = (text[b * S_LEN + s] != 0);
    if (j < NTAG) {
      const float v0 = a0 + tr0, v1 = a1 + tr1, v2 = a2 + tr2, v3 = a3 + tr3, v4 = a4 + tr4;
      float mx = fmaxf(fmaxf(fmaxf(v0, v1), fmaxf(v2, v3)), v4);
      float sm = expf(v0 - mx) + expf(v1 - mx) + expf(v2 - mx) + expf(v3 - mx) + expf(v4 - mx);
      float nxt = mx + logf(sm) + em[((size_t)s * BATCH + b) * NTAG + j];
      if (m) alpha = nxt;
    }
  }
  float v  = (j < NTAG) ? (alpha + en) : -1e30f;
  float mx = v;
  #pragma unroll
  for (int off = 1; off < 8; off <<= 1) mx = fmaxf(mx, __shfl_xor(mx, off));
  float ex = (j < NTAG) ? expf(v - mx) : 0.f;
  #pragma unroll
  for (int off = 1; off < 8; off <<= 1) ex += __shfl_xor(ex, off);
  if (j == 0) {
    perb[c * BATCH + b] = num - (mx + logf(ex));
    cntb[c * BATCH + b] = cnt;
  }
}

// ---------------- final reduction ----------------
__global__ void k_final(const float* __restrict__ perb, const float* __restrict__ cntb,
                        float* __restrict__ out)
{
  if (threadIdx.x == 0 && blockIdx.x == 0) {
    float s0 = 0, c0 = 0, s1 = 0, c1 = 0;
    for (int b = 0; b < BATCH; ++b) {
      s0 += perb[b];         c0 += cntb[b];
      s1 += perb[BATCH + b]; c1 += cntb[BATCH + b];
    }
    const float ls = -s0 / c0, lo = -s1 / c1;
    out[0] = 2.f * (ls + lo);
    out[1] = ls;
    out[2] = lo;
  }
}

extern "C" void kernel_launch(void* const* d_in, const int* in_sizes, int n_in,
                              void* d_out, int out_size, void* d_ws, size_t ws_size,
                              hipStream_t stream)
{
  const int*   text  = (const int*)d_in[0];
  const int*   sbjs  = (const int*)d_in[1];
  const int*   objs  = (const int*)d_in[2];
  const float* emb   = (const float*)d_in[3];
  const float* wih_f = (const float*)d_in[4];
  const float* whh_f = (const float*)d_in[5];
  const float* bih_f = (const float*)d_in[6];
  const float* bhh_f = (const float*)d_in[7];
  const float* wih_b = (const float*)d_in[8];
  const float* whh_b = (const float*)d_in[9];
  const float* bih_b = (const float*)d_in[10];
  const float* bhh_b = (const float*)d_in[11];
  const float* sbj_w = (const float*)d_in[12];
  const float* sbj_b = (const float*)d_in[13];
  const float* obj_w = (const float*)d_in[14];
  const float* obj_b = (const float*)d_in[15];
  const float* s_st  = (const float*)d_in[16];
  const float* s_en  = (const float*)d_in[17];
  const float* s_tr  = (const float*)d_in[18];
  const float* o_st  = (const float*)d_in[19];
  const float* o_en  = (const float*)d_in[20];
  const float* o_tr  = (const float*)d_in[21];

  char* w = (char*)d_ws;
  float*          x     = (float*)(w + 0);               // 33,554,432 B
  __hip_bfloat16* vec   = (__hip_bfloat16*)(w + 33554432);  // 67,108,864 B
  float*          h_buf = (float*)(w + 100663296);       //  1,048,576 B
  float*          em_s  = (float*)(w + 101711872);       //    655,360 B
  float*          em_o  = (float*)(w + 102367232);       //    655,360 B
  float*          perb  = (float*)(w + 103022592);       //        512 B
  float*          cntb  = (float*)(w + 103023104);       //        512 B
  int*            bar   = (int*)(w + 103023616);         //        256 B

  hipMemsetAsync(h_buf, 0, 2 * 2 * BATCH * HID * sizeof(float), stream);
  hipMemsetAsync(bar, 0, 256, stream);

  k_embed<<<2048, 256, 0, stream>>>(text, emb, x);

  const int smem_bytes = (16 * 772 + 16 + 64 * 132) * 4;  // 83,264 B -> 1 block/CU
  hipFuncSetAttribute((const void*)k_lstm, hipFuncAttributeMaxDynamicSharedMemorySize,
                      smem_bytes);
  void* args[] = { (void*)&x, (void*)&wih_f, (void*)&whh_f, (void*)&bih_f, (void*)&bhh_f,
                   (void*)&wih_b, (void*)&whh_b, (void*)&bih_b, (void*)&bhh_b,
                   (void*)&h_buf, (void*)&vec, (void*)&bar };
  hipLaunchCooperativeKernel((const void*)k_lstm, dim3(256), dim3(256), args,
                             (unsigned int)smem_bytes, stream);

  k_heads<<<8192, 256, 0, stream>>>(vec, sbj_w, sbj_b, obj_w, obj_b, em_s, em_o);
  k_crf<<<128, 64, 0, stream>>>(em_s, em_o, sbjs, objs, text,
                                s_st, s_en, s_tr, o_st, o_en, o_tr, perb, cntb);
  k_final<<<1, 1, 0, stream>>>(perb, cntb, (float*)d_out);
}

// Round 3
// 5503.774 us; speedup vs baseline: 4.9755x; 4.9755x over previous
//
#include <hip/hip_runtime.h>
#include <hip/hip_bf16.h>

#define S_LEN 512
#define BATCH 64
#define EMB_D 256
#define HID   512
#define NTAG  5

typedef unsigned short u16;
typedef __attribute__((ext_vector_type(8)))  short bf16x8;
typedef __attribute__((ext_vector_type(16))) float f32x16;

__device__ __forceinline__ float bf2f(u16 u) {
  union { unsigned int i; float f; } v; v.i = ((unsigned int)u) << 16; return v.f;
}
__device__ __forceinline__ u16 f2bf(float f) {
  __hip_bfloat16 h = __float2bfloat16(f);
  union { __hip_bfloat16 h; u16 u; } v; v.h = h; return v.u;
}
__device__ __forceinline__ float sigm(float x) { return 1.0f / (1.0f + __expf(-x)); }
__device__ __forceinline__ float ftanh(float x) {
  float ax = fabsf(x);
  float e  = __expf(-2.0f * ax);
  float t  = (1.0f - e) / (1.0f + e);
  return copysignf(t, x);
}

// ---------------- weight prep: Wcat bf16 [2][2048][768] = [Wih | Whh], bias fp32 [2][2048]
__global__ void k_prep_w(const float* __restrict__ wihf, const float* __restrict__ whhf,
                         const float* __restrict__ bihf, const float* __restrict__ bhhf,
                         const float* __restrict__ wihb, const float* __restrict__ whhb,
                         const float* __restrict__ bihb, const float* __restrict__ bhhb,
                         u16* __restrict__ Wcat, float* __restrict__ bias)
{
  const int gid = blockIdx.x * blockDim.x + threadIdx.x;   // 786432 groups of 4
  const int k4  = gid % 192;
  const int rem = gid / 192;
  const int row = rem & 2047;
  const int d   = rem >> 11;
  const float* wih = d ? wihb : wihf;
  const float* whh = d ? whhb : whhf;
  const int k = k4 * 4;
  float4 v;
  if (k < EMB_D) v = *(const float4*)(wih + (size_t)row * EMB_D + k);
  else           v = *(const float4*)(whh + (size_t)row * HID + (k - EMB_D));
  union { u16 u[4]; uint2 q; } pk;
  pk.u[0] = f2bf(v.x); pk.u[1] = f2bf(v.y); pk.u[2] = f2bf(v.z); pk.u[3] = f2bf(v.w);
  *(uint2*)(Wcat + ((size_t)(d * 2048 + row)) * 768 + k) = pk.q;
  if (gid < 4096) {
    const int dd = gid >> 11, r = gid & 2047;
    bias[gid] = dd ? (bihb[r] + bhhb[r]) : (bihf[r] + bhhf[r]);
  }
}

// ---------------- embedding gather -> xz bf16 [S][B][EMB]
__global__ void k_embed(const int* __restrict__ text, const float* __restrict__ emb,
                        u16* __restrict__ xz)
{
  const int gid = blockIdx.x * blockDim.x + threadIdx.x;   // 2,097,152 groups of 4
  const int e4 = gid & 63;
  const int sb = gid >> 6;
  const int b  = sb & 63;
  const int s  = sb >> 6;
  const int row = text[b * S_LEN + s];
  float4 v = *(const float4*)(emb + (size_t)row * EMB_D + e4 * 4);
  union { u16 u[4]; uint2 q; } pk;
  pk.u[0] = f2bf(v.x); pk.u[1] = f2bf(v.y); pk.u[2] = f2bf(v.z); pk.u[3] = f2bf(v.w);
  *(uint2*)(xz + ((size_t)(s * BATCH + b)) * EMB_D + e4 * 4) = pk.q;
}

// ---------------- persistent MFMA BiLSTM ----------------
// 64 blocks: d = bid>>5, hid slice k0 = (bid&31)*16 (16 hidden units, 64 gate rows).
// 4 waves: mt = w>>1 (gates {0,1} or {2,3}), nt = w&1 (batch cols 0-31 / 32-63).
// A fragments (48 x bf16x8 = 192 VGPR) persistent in registers.
__launch_bounds__(256, 1)
__global__ void k_lstm(const u16* __restrict__ Wcat, const float* __restrict__ bias,
                       const u16* __restrict__ xz, u16* __restrict__ hbuf,
                       int* __restrict__ cnt)
{
  __shared__ float gbuf[64 * 66];   // [gate*16+hid][batch], stride 66 (2-way max conflicts)

  const int bid = blockIdx.x;
  const int d   = bid >> 5;
  const int k0  = (bid & 31) * 16;
  const int tid = threadIdx.x;
  const int w    = tid >> 6;
  const int lane = tid & 63;
  const int mt = w >> 1, nt = w & 1;
  const int ln31 = lane & 31, lhi = lane >> 5;

  // ---- load A fragments once (rows: m=lane&31 -> gate q=mt*2+(m>>4), hid m&15) ----
  bf16x8 af[48];
  {
    const int m    = ln31;
    const int q    = mt * 2 + (m >> 4);
    const int grow = q * HID + k0 + (m & 15);
    const u16* wr  = Wcat + ((size_t)(d * 2048 + grow)) * 768 + lhi * 8;
    #pragma unroll
    for (int ks = 0; ks < 48; ++ks) af[ks] = *(const bf16x8*)(wr + ks * 16);
  }

  // ---- elementwise thread mapping: b = tid>>2, hid base = (tid&3)*4 ----
  const int eb = tid >> 2;
  const int eh = (tid & 3) * 4;
  float bsv[4][4];
  #pragma unroll
  for (int q = 0; q < 4; ++q)
    #pragma unroll
    for (int i = 0; i < 4; ++i)
      bsv[q][i] = bias[d * 2048 + q * HID + k0 + eh + i];
  float cst[4] = {0.f, 0.f, 0.f, 0.f};

  for (int it = 0; it < S_LEN; ++it) {
    const int t = d ? (S_LEN - 1 - it) : it;
    f32x16 acc;
    #pragma unroll
    for (int r = 0; r < 16; ++r) acc[r] = 0.f;

    // ---- x-part (independent of h) ----
    {
      const u16* xb = xz + ((size_t)t * BATCH + nt * 32 + ln31) * EMB_D + lhi * 8;
      #pragma unroll
      for (int c = 0; c < 2; ++c) {
        bf16x8 bfr[8];
        #pragma unroll
        for (int j = 0; j < 8; ++j) bfr[j] = *(const bf16x8*)(xb + (c * 8 + j) * 16);
        #pragma unroll
        for (int j = 0; j < 8; ++j)
          acc = __builtin_amdgcn_mfma_f32_32x32x16_bf16(af[c * 8 + j], bfr[j], acc, 0, 0, 0);
      }
    }

    // ---- wait for h_{t_prev}, then h-part ----
    if (it > 0) {
      if (tid == 0) {
        int* p = cnt + ((d << 9) + it - 1) * 16;
        while (__hip_atomic_load(p, __ATOMIC_RELAXED, __HIP_MEMORY_SCOPE_AGENT) < 32)
          __builtin_amdgcn_s_sleep(1);
        __threadfence();
      }
      __syncthreads();
      const int tprev = d ? (t + 1) : (t - 1);
      const u16* hb = hbuf + (((size_t)(d << 9) + tprev) * BATCH + nt * 32 + ln31) * HID + lhi * 8;
      #pragma unroll
      for (int c = 0; c < 4; ++c) {
        bf16x8 bfr[8];
        #pragma unroll
        for (int j = 0; j < 8; ++j) bfr[j] = *(const bf16x8*)(hb + (c * 8 + j) * 16);
        #pragma unroll
        for (int j = 0; j < 8; ++j)
          acc = __builtin_amdgcn_mfma_f32_32x32x16_bf16(af[16 + c * 8 + j], bfr[j], acc, 0, 0, 0);
      }
    }

    // ---- exchange gates via LDS ----
    #pragma unroll
    for (int r = 0; r < 16; ++r) {
      const int grl = (r & 3) + 8 * (r >> 2) + 4 * lhi;   // row within 32-tile
      const int q   = mt * 2 + (grl >> 4);
      const int hid = grl & 15;
      gbuf[(q * 16 + hid) * 66 + nt * 32 + ln31] = acc[r];
    }
    __syncthreads();

    // ---- elementwise LSTM cell + h write (packed 8B bf16) ----
    union { u16 u[4]; uint2 q; } pk;
    #pragma unroll
    for (int i = 0; i < 4; ++i) {
      const int hl = eh + i;
      const float gi = gbuf[(0  + hl) * 66 + eb] + bsv[0][i];
      const float gf = gbuf[(16 + hl) * 66 + eb] + bsv[1][i];
      const float gg = gbuf[(32 + hl) * 66 + eb] + bsv[2][i];
      const float go = gbuf[(48 + hl) * 66 + eb] + bsv[3][i];
      const float ig = sigm(gi), fg = sigm(gf), g2 = ftanh(gg), og = sigm(go);
      cst[i] = fg * cst[i] + ig * g2;
      pk.u[i] = f2bf(og * ftanh(cst[i]));
    }
    *(uint2*)(hbuf + (((size_t)(d << 9) + t) * BATCH + eb) * HID + k0 + eh) = pk.q;
    __syncthreads();
    if (tid == 0) {
      __threadfence();
      atomicAdd(cnt + ((d << 9) + it) * 16, 1);
    }
  }
}

// ---------------- heads: em[s][b][j] = [hf;hb] . w[j] + bias[j] ----------------
__global__ void k_heads(const u16* __restrict__ hbuf,
                        const float* __restrict__ sbj_w, const float* __restrict__ sbj_b,
                        const float* __restrict__ obj_w, const float* __restrict__ obj_b,
                        float* __restrict__ em_s, float* __restrict__ em_o)
{
  const int wid  = blockIdx.x * 4 + (threadIdx.x >> 6);
  const int lane = threadIdx.x & 63;
  if (wid >= S_LEN * BATCH) return;
  const int s = wid >> 6, b = wid & 63;
  const int dsel = lane >> 5;
  const int off  = (lane * 16) & 511;
  const u16* src = hbuf + (((size_t)(dsel << 9) + s) * BATCH + b) * HID + off;
  uint4 p0 = *(const uint4*)(src);
  uint4 p1 = *(const uint4*)(src + 8);
  unsigned int pw[8] = { p0.x, p0.y, p0.z, p0.w, p1.x, p1.y, p1.z, p1.w };
  float z[16];
  #pragma unroll
  for (int i = 0; i < 8; ++i) {
    z[2 * i]     = bf2f((u16)(pw[i] & 0xffffu));
    z[2 * i + 1] = bf2f((u16)(pw[i] >> 16));
  }
  #pragma unroll
  for (int r = 0; r < 10; ++r) {
    const float* wr = (r < 5) ? (sbj_w + r * (2 * HID)) : (obj_w + (r - 5) * (2 * HID));
    float p = 0.f;
    #pragma unroll
    for (int m4 = 0; m4 < 4; ++m4) {
      float4 w4 = *(const float4*)(wr + lane * 16 + m4 * 4);
      p += w4.x * z[m4*4] + w4.y * z[m4*4+1] + w4.z * z[m4*4+2] + w4.w * z[m4*4+3];
    }
    #pragma unroll
    for (int offs = 32; offs; offs >>= 1) p += __shfl_down(p, offs);
    if (lane == 0) {
      if (r < 5) em_s[(size_t)wid * NTAG + r]       = p + sbj_b[r];
      else       em_o[(size_t)wid * NTAG + (r - 5)] = p + obj_b[r - 5];
    }
  }
}

// ---------------- CRF NLL per (crf, batch): one wave each ----------------
__global__ void k_crf(const float* __restrict__ em_s, const float* __restrict__ em_o,
                      const int* __restrict__ sbjs, const int* __restrict__ objs,
                      const int* __restrict__ text,
                      const float* __restrict__ s_st, const float* __restrict__ s_en,
                      const float* __restrict__ s_tr,
                      const float* __restrict__ o_st, const float* __restrict__ o_en,
                      const float* __restrict__ o_tr,
                      float* __restrict__ perb, float* __restrict__ cntb)
{
  const int c = blockIdx.x & 1;
  const int b = blockIdx.x >> 1;
  const int j = threadIdx.x;

  const float* em    = c ? em_o : em_s;
  const int*   tags  = c ? objs : sbjs;
  const float* start = c ? o_st : s_st;
  const float* endv  = c ? o_en : s_en;
  const float* trans = c ? o_tr : s_tr;

  float num = 0.f, cnt = 0.f;
  for (int s = j; s < S_LEN; s += 64) {
    const int m = (text[b * S_LEN + s] != 0) ? 1 : 0;
    cnt += (float)m;
    const int tg = tags[b * S_LEN + s];
    if (s == 0) {
      num += start[tg] + em[(size_t)b * NTAG + tg];
    } else if (m) {
      const int tp = tags[b * S_LEN + s - 1];
      num += trans[tp * NTAG + tg] + em[((size_t)s * BATCH + b) * NTAG + tg];
    }
  }
  #pragma unroll
  for (int off = 32; off; off >>= 1) { num += __shfl_down(num, off); cnt += __shfl_down(cnt, off); }
  num = __shfl(num, 0); cnt = __shfl(cnt, 0);
  const int seq_end = (int)cnt - 1;
  if (j == 0) num += endv[tags[b * S_LEN + seq_end]];

  float tr0 = 0, tr1 = 0, tr2 = 0, tr3 = 0, tr4 = 0, st = 0, en = 0;
  if (j < NTAG) {
    tr0 = trans[0 * NTAG + j]; tr1 = trans[1 * NTAG + j]; tr2 = trans[2 * NTAG + j];
    tr3 = trans[3 * NTAG + j]; tr4 = trans[4 * NTAG + j];
    st = start[j]; en = endv[j];
  }
  float alpha = (j < NTAG) ? (st + em[(size_t)b * NTAG + j]) : -1e30f;
  for (int s = 1; s < S_LEN; ++s) {
    const float a0 = __shfl(alpha, 0), a1 = __shfl(alpha, 1), a2 = __shfl(alpha, 2),
                a3 = __shfl(alpha, 3), a4 = __shfl(alpha, 4);
    const int m = (text[b * S_LEN + s] != 0);
    if (j < NTAG) {
      const float v0 = a0 + tr0, v1 = a1 + tr1, v2 = a2 + tr2, v3 = a3 + tr3, v4 = a4 + tr4;
      float mx = fmaxf(fmaxf(fmaxf(v0, v1), fmaxf(v2, v3)), v4);
      float sm = expf(v0 - mx) + expf(v1 - mx) + expf(v2 - mx) + expf(v3 - mx) + expf(v4 - mx);
      float nxt = mx + logf(sm) + em[((size_t)s * BATCH + b) * NTAG + j];
      if (m) alpha = nxt;
    }
  }
  float v  = (j < NTAG) ? (alpha + en) : -1e30f;
  float mx = v;
  #pragma unroll
  for (int off = 1; off < 8; off <<= 1) mx = fmaxf(mx, __shfl_xor(mx, off));
  float ex = (j < NTAG) ? expf(v - mx) : 0.f;
  #pragma unroll
  for (int off = 1; off < 8; off <<= 1) ex += __shfl_xor(ex, off);
  if (j == 0) {
    perb[c * BATCH + b] = num - (mx + logf(ex));
    cntb[c * BATCH + b] = cnt;
  }
}

__global__ void k_final(const float* __restrict__ perb, const float* __restrict__ cntb,
                        float* __restrict__ out)
{
  if (threadIdx.x == 0 && blockIdx.x == 0) {
    float s0 = 0, c0 = 0, s1 = 0, c1 = 0;
    for (int b = 0; b < BATCH; ++b) {
      s0 += perb[b];         c0 += cntb[b];
      s1 += perb[BATCH + b]; c1 += cntb[BATCH + b];
    }
    const float ls = -s0 / c0, lo = -s1 / c1;
    out[0] = 2.f * (ls + lo);
    out[1] = ls;
    out[2] = lo;
  }
}

extern "C" void kernel_launch(void* const* d_in, const int* in_sizes, int n_in,
                              void* d_out, int out_size, void* d_ws, size_t ws_size,
                              hipStream_t stream)
{
  const int*   text  = (const int*)d_in[0];
  const int*   sbjs  = (const int*)d_in[1];
  const int*   objs  = (const int*)d_in[2];
  const float* emb   = (const float*)d_in[3];
  const float* wih_f = (const float*)d_in[4];
  const float* whh_f = (const float*)d_in[5];
  const float* bih_f = (const float*)d_in[6];
  const float* bhh_f = (const float*)d_in[7];
  const float* wih_b = (const float*)d_in[8];
  const float* whh_b = (const float*)d_in[9];
  const float* bih_b = (const float*)d_in[10];
  const float* bhh_b = (const float*)d_in[11];
  const float* sbj_w = (const float*)d_in[12];
  const float* sbj_b = (const float*)d_in[13];
  const float* obj_w = (const float*)d_in[14];
  const float* obj_b = (const float*)d_in[15];
  const float* s_st  = (const float*)d_in[16];
  const float* s_en  = (const float*)d_in[17];
  const float* s_tr  = (const float*)d_in[18];
  const float* o_st  = (const float*)d_in[19];
  const float* o_en  = (const float*)d_in[20];
  const float* o_tr  = (const float*)d_in[21];

  char* w = (char*)d_ws;
  u16*   Wcat = (u16*)(w + 0);            //  6,291,456 B
  float* bias = (float*)(w + 6291456);    //     16,384 B
  u16*   xz   = (u16*)(w + 6307840);      // 16,777,216 B
  u16*   hbuf = (u16*)(w + 23085056);     // 67,108,864 B
  float* em_s = (float*)(w + 90193920);   //    655,360 B
  float* em_o = (float*)(w + 90849280);   //    655,360 B
  float* perb = (float*)(w + 91504640);   //        512 B
  float* cntb = (float*)(w + 91505152);   //        512 B
  int*   cnt  = (int*)(w + 91505664);     //     65,536 B

  hipMemsetAsync(cnt, 0, 2 * 512 * 16 * sizeof(int), stream);

  k_prep_w<<<3072, 256, 0, stream>>>(wih_f, whh_f, bih_f, bhh_f,
                                     wih_b, whh_b, bih_b, bhh_b, Wcat, bias);
  k_embed<<<8192, 256, 0, stream>>>(text, emb, xz);

  void* args[] = { (void*)&Wcat, (void*)&bias, (void*)&xz, (void*)&hbuf, (void*)&cnt };
  hipLaunchCooperativeKernel((const void*)k_lstm, dim3(64), dim3(256), args, 0, stream);

  k_heads<<<8192, 256, 0, stream>>>(hbuf, sbj_w, sbj_b, obj_w, obj_b, em_s, em_o);
  k_crf<<<128, 64, 0, stream>>>(em_s, em_o, sbjs, objs, text,
                                s_st, s_en, s_tr, o_st, o_en, o_tr, perb, cntb);
  k_final<<<1, 1, 0, stream>>>(perb, cntb, (float*)d_out);
}